// Round 1
// baseline (467.693 us; speedup 1.0000x reference)
//
#include <hip/hip_runtime.h>
#include <hip/hip_bf16.h>

#define M_DIM 32768   // SEQ*BATCH = 8192*4
#define N_DIM 4096    // D_OUT
#define K_DIM 1024    // D_IN
#define BM 128
#define BN 128
#define BK 64
#define NKT (K_DIM / BK)                    // 16
#define TILES_N (N_DIM / BN)                // 32
#define NWG ((M_DIM / BM) * (N_DIM / BN))   // 8192

typedef __attribute__((ext_vector_type(4))) float f32x4;
typedef __attribute__((ext_vector_type(8))) short bf16x8;

__device__ __forceinline__ unsigned short f2bf(float f) {
    unsigned int u = __float_as_uint(f);
    u += 0x7FFFu + ((u >> 16) & 1u);   // round-to-nearest-even
    return (unsigned short)(u >> 16);
}

__device__ __forceinline__ void gld_lds16(const void* gsrc, void* ldst) {
    __builtin_amdgcn_global_load_lds(
        (__attribute__((address_space(1))) void*)gsrc,
        (__attribute__((address_space(3))) void*)ldst,
        16, 0, 0);
}

// fp32 -> bf16 pre-cast of X and W into workspace (linear [row][k] layout).
__global__ void cast_kernel(const float* __restrict__ x, const float* __restrict__ w,
                            unsigned short* __restrict__ wsA, unsigned short* __restrict__ wsB) {
    const int nA = M_DIM * (K_DIM / 8);   // 16B bf16 groups in A
    const int nB = N_DIM * (K_DIM / 8);
    const int total = nA + nB;
    const int stride = gridDim.x * blockDim.x;
    for (int i = blockIdx.x * blockDim.x + threadIdx.x; i < total; i += stride) {
        const float* src; unsigned short* dst; int g;
        if (i < nA) { src = x; dst = wsA; g = i; }
        else        { src = w; dst = wsB; g = i - nA; }
        const f32x4* s4 = (const f32x4*)(src + (size_t)g * 8);
        f32x4 v0 = s4[0];
        f32x4 v1 = s4[1];
        bf16x8 o;
        o[0] = (short)f2bf(v0[0]); o[1] = (short)f2bf(v0[1]);
        o[2] = (short)f2bf(v0[2]); o[3] = (short)f2bf(v0[3]);
        o[4] = (short)f2bf(v1[0]); o[5] = (short)f2bf(v1[1]);
        o[6] = (short)f2bf(v1[2]); o[7] = (short)f2bf(v1[3]);
        *(bf16x8*)(dst + (size_t)g * 8) = o;
    }
}

// C = A(MxK) * B(NxK)^T + bias.  128x128 tile, BK=64, 4 waves of 64x64.
// LDS tile layout: [row][k8slot] with slot ^= (row&7) XOR swizzle; staging
// writes are LDS-linear (global_load_lds requirement), the swizzle is applied
// on the global SOURCE address, and again on ds_read (both-sides rule).
template<bool PRE>
__global__ __launch_bounds__(256, 2)
void gemm_kernel(const void* __restrict__ Ap, const void* __restrict__ Bp,
                 const float* __restrict__ bias, float* __restrict__ C) {
    __shared__ unsigned char smem[2 * 32768];   // 2 buffers x (A 16KiB + B 16KiB)

    const int t    = threadIdx.x;
    const int lane = t & 63;
    const int wave = t >> 6;
    const int wr   = wave >> 1;     // wave row (0..1)
    const int wc   = wave & 1;      // wave col (0..1)

    // XCD-aware bijective swizzle (NWG % 8 == 0)
    const int bid  = blockIdx.x;
    const int swz  = (bid & 7) * (NWG / 8) + (bid >> 3);
    const int row0 = (swz / TILES_N) * BM;
    const int col0 = (swz % TILES_N) * BN;

    // staging geometry: thread t covers segs (i*256+t); row = i*32 + (t>>3),
    // lds slot s = t&7, sourced from global k8-slot j = s ^ (row&7).
    const int srow  = t >> 3;                    // 0..31
    const int sj    = (t & 7) ^ (srow & 7);
    const int aoff0 = (row0 + srow) * K_DIM + sj * 8;
    const int boff0 = (col0 + srow) * K_DIM + sj * 8;

    f32x4 acc[4][4] = {};

    const int laneR = lane & 15;
    const int jb    = lane >> 4;
    const int lx    = lane & 7;

    // compute one K-step (BK=64) from LDS buffer `cur`
    auto compute = [&](int cur) {
        #pragma unroll
        for (int kk = 0; kk < 2; ++kk) {
            bf16x8 af[4], bfr[4];
            #pragma unroll
            for (int m = 0; m < 4; ++m) {
                const int r = wr * 64 + m * 16 + laneR;
                af[m] = *(const bf16x8*)(smem + cur * 32768 + r * 128
                                         + (((kk * 4 + jb) ^ lx) * 16));
            }
            #pragma unroll
            for (int n = 0; n < 4; ++n) {
                const int r = wc * 64 + n * 16 + laneR;
                bfr[n] = *(const bf16x8*)(smem + cur * 32768 + 16384 + r * 128
                                          + (((kk * 4 + jb) ^ lx) * 16));
            }
            #pragma unroll
            for (int m = 0; m < 4; ++m)
                #pragma unroll
                for (int n = 0; n < 4; ++n)
                    acc[m][n] = __builtin_amdgcn_mfma_f32_16x16x32_bf16(
                        af[m], bfr[n], acc[m][n], 0, 0, 0);
        }
    };

    if constexpr (PRE) {
        const unsigned short* Abf = (const unsigned short*)Ap;
        const unsigned short* Bbf = (const unsigned short*)Bp;

        auto stage = [&](int buf, int kt) {
            const int kofs = kt * BK;
            #pragma unroll
            for (int i = 0; i < 4; ++i) {
                gld_lds16(Abf + aoff0 + i * (32 * K_DIM) + kofs,
                          smem + buf * 32768 + i * 4096 + wave * 1024);
                gld_lds16(Bbf + boff0 + i * (32 * K_DIM) + kofs,
                          smem + buf * 32768 + 16384 + i * 4096 + wave * 1024);
            }
        };

        stage(0, 0);
        __syncthreads();
        for (int kt = 0; kt < NKT; ++kt) {
            const int cur = kt & 1;
            if (kt + 1 < NKT) stage(cur ^ 1, kt + 1);   // async, in flight across compute
            compute(cur);
            __syncthreads();                            // drains vmcnt: next buffer ready
        }
    } else {
        // fallback: fused fp32->bf16 reg-staging (no workspace needed)
        const float* Af = (const float*)Ap;
        const float* Bf = (const float*)Bp;
        f32x4 ra[4][2], rb[4][2];

        auto load_regs = [&](int kt) {
            const int kofs = kt * BK;
            #pragma unroll
            for (int i = 0; i < 4; ++i) {
                const float* pa = Af + aoff0 + i * (32 * K_DIM) + kofs;
                ra[i][0] = *(const f32x4*)pa;
                ra[i][1] = *(const f32x4*)(pa + 4);
                const float* pb = Bf + boff0 + i * (32 * K_DIM) + kofs;
                rb[i][0] = *(const f32x4*)pb;
                rb[i][1] = *(const f32x4*)(pb + 4);
            }
        };
        auto write_lds = [&](int buf) {
            #pragma unroll
            for (int i = 0; i < 4; ++i) {
                bf16x8 oa, ob;
                #pragma unroll
                for (int q = 0; q < 4; ++q) {
                    oa[q]     = (short)f2bf(ra[i][0][q]);
                    oa[q + 4] = (short)f2bf(ra[i][1][q]);
                    ob[q]     = (short)f2bf(rb[i][0][q]);
                    ob[q + 4] = (short)f2bf(rb[i][1][q]);
                }
                *(bf16x8*)(smem + buf * 32768 + i * 4096 + t * 16) = oa;
                *(bf16x8*)(smem + buf * 32768 + 16384 + i * 4096 + t * 16) = ob;
            }
        };

        load_regs(0);
        write_lds(0);
        __syncthreads();
        for (int kt = 0; kt < NKT; ++kt) {
            const int cur = kt & 1;
            if (kt + 1 < NKT) load_regs(kt + 1);   // issue early (T14)
            compute(cur);
            if (kt + 1 < NKT) write_lds(cur ^ 1);  // write late, after compute
            __syncthreads();
        }
    }

    // epilogue: C/D layout col = lane&15, row = (lane>>4)*4 + reg
    const int cr = (lane >> 4) * 4;
    const int cc = lane & 15;
    float bv[4];
    #pragma unroll
    for (int n = 0; n < 4; ++n)
        bv[n] = bias[col0 + wc * 64 + n * 16 + cc];
    #pragma unroll
    for (int m = 0; m < 4; ++m) {
        const int gr = row0 + wr * 64 + m * 16 + cr;
        #pragma unroll
        for (int n = 0; n < 4; ++n) {
            const int gc = col0 + wc * 64 + n * 16 + cc;
            float* p = C + (size_t)gr * N_DIM + gc;
            p[0]                  = acc[m][n][0] + bv[n];
            p[(size_t)N_DIM]      = acc[m][n][1] + bv[n];
            p[(size_t)2 * N_DIM]  = acc[m][n][2] + bv[n];
            p[(size_t)3 * N_DIM]  = acc[m][n][3] + bv[n];
        }
    }
}

extern "C" void kernel_launch(void* const* d_in, const int* in_sizes, int n_in,
                              void* d_out, int out_size, void* d_ws, size_t ws_size,
                              hipStream_t stream) {
    const float* x    = (const float*)d_in[0];
    const float* w    = (const float*)d_in[1];
    const float* bias = (const float*)d_in[2];
    float* out        = (float*)d_out;

    const size_t needA = (size_t)M_DIM * K_DIM * sizeof(unsigned short);
    const size_t needB = (size_t)N_DIM * K_DIM * sizeof(unsigned short);

    if (ws_size >= needA + needB) {
        unsigned short* wsA = (unsigned short*)d_ws;
        unsigned short* wsB = wsA + (size_t)M_DIM * K_DIM;
        cast_kernel<<<4096, 256, 0, stream>>>(x, w, wsA, wsB);
        gemm_kernel<true><<<NWG, 256, 0, stream>>>(wsA, wsB, bias, out);
    } else {
        gemm_kernel<false><<<NWG, 256, 0, stream>>>(x, w, bias, out);
    }
}

// Round 2
// 350.699 us; speedup vs baseline: 1.3336x; 1.3336x over previous
//
#include <hip/hip_runtime.h>
#include <hip/hip_bf16.h>

#define M_DIM 32768   // SEQ*BATCH = 8192*4
#define N_DIM 4096    // D_OUT
#define K_DIM 1024    // D_IN
#define BM 128
#define BN 128
#define BK 64
#define NKT (K_DIM / BK)                    // 16
#define TILES_N (N_DIM / BN)                // 32
#define NWG ((M_DIM / BM) * (N_DIM / BN))   // 8192

typedef __attribute__((ext_vector_type(4))) float f32x4;
typedef __attribute__((ext_vector_type(8))) short bf16x8;

__device__ __forceinline__ unsigned short f2bf(float f) {
    unsigned int u = __float_as_uint(f);
    u += 0x7FFFu + ((u >> 16) & 1u);   // round-to-nearest-even
    return (unsigned short)(u >> 16);
}

__device__ __forceinline__ void gld_lds16(const void* gsrc, void* ldst) {
    __builtin_amdgcn_global_load_lds(
        (__attribute__((address_space(1))) void*)gsrc,
        (__attribute__((address_space(3))) void*)ldst,
        16, 0, 0);
}

// fp32 -> bf16 pre-cast of X and W into workspace (linear [row][k] layout).
__global__ void cast_kernel(const float* __restrict__ x, const float* __restrict__ w,
                            unsigned short* __restrict__ wsA, unsigned short* __restrict__ wsB) {
    const int nA = M_DIM * (K_DIM / 8);   // 16B bf16 groups in A
    const int nB = N_DIM * (K_DIM / 8);
    const int total = nA + nB;
    const int stride = gridDim.x * blockDim.x;
    for (int i = blockIdx.x * blockDim.x + threadIdx.x; i < total; i += stride) {
        const float* src; unsigned short* dst; int g;
        if (i < nA) { src = x; dst = wsA; g = i; }
        else        { src = w; dst = wsB; g = i - nA; }
        const f32x4* s4 = (const f32x4*)(src + (size_t)g * 8);
        f32x4 v0 = s4[0];
        f32x4 v1 = s4[1];
        bf16x8 o;
        o[0] = (short)f2bf(v0[0]); o[1] = (short)f2bf(v0[1]);
        o[2] = (short)f2bf(v0[2]); o[3] = (short)f2bf(v0[3]);
        o[4] = (short)f2bf(v1[0]); o[5] = (short)f2bf(v1[1]);
        o[6] = (short)f2bf(v1[2]); o[7] = (short)f2bf(v1[3]);
        *(bf16x8*)(dst + (size_t)g * 8) = o;
    }
}

// C = A(MxK) * B(NxK)^T + bias.  128x128 tile, BK=64, 4 waves of 64x64.
// m97 structure: SINGLE-buffered 32 KiB LDS, stage -> barrier -> compute ->
// barrier (the __syncthreads drain supplies the vmcnt(0)); occupancy 4
// blocks/CU does the cross-wave pipelining (m99/m100: explicit dbuf adds
// nothing but here double-buffer LDS halved occupancy).
// LDS tile layout: [row][k8slot] with slot ^= (row&7) XOR swizzle; staging
// writes are LDS-linear (global_load_lds requirement), the swizzle is applied
// on the global SOURCE address, and again on ds_read (both-sides rule).
template<bool PRE>
__global__ __launch_bounds__(256, 4)
void gemm_kernel(const void* __restrict__ Ap, const void* __restrict__ Bp,
                 const float* __restrict__ bias, float* __restrict__ C) {
    __shared__ unsigned char smem[32768];   // A 16KiB + B 16KiB, single buffer

    const int t    = threadIdx.x;
    const int lane = t & 63;
    const int wave = t >> 6;
    const int wr   = wave >> 1;     // wave row (0..1)
    const int wc   = wave & 1;      // wave col (0..1)

    // XCD-aware mapping + within-XCD 8x8 super-tile (L2 blocking):
    // per XCD: 1024 tiles = 16 super-tiles of 64 blocks (8 tile-rows x 8
    // tile-cols). A panel 2 MiB + B panel 2 MiB fits the 4 MiB per-XCD L2.
    const int bid  = blockIdx.x;
    const int xcd  = bid & 7;
    const int j    = bid >> 3;              // 0..1023
    const int st   = j >> 6;                // 0..15
    const int w    = j & 63;                // 0..63
    const int trow = xcd * 32 + (st >> 2) * 8 + (w >> 3);
    const int tcol = (st & 3) * 8 + (w & 7);
    const int row0 = trow * BM;
    const int col0 = tcol * BN;

    // staging geometry: thread t covers segs (i*256+t); row = i*32 + (t>>3),
    // lds slot s = t&7, sourced from global k8-slot j = s ^ (row&7).
    const int srow  = t >> 3;                    // 0..31
    const int sj    = (t & 7) ^ (srow & 7);
    const int aoff0 = (row0 + srow) * K_DIM + sj * 8;
    const int boff0 = (col0 + srow) * K_DIM + sj * 8;

    f32x4 acc[4][4] = {};

    const int laneR = lane & 15;
    const int jb    = lane >> 4;
    const int lx    = lane & 7;

    // compute one K-step (BK=64) from the LDS buffer
    auto compute = [&]() {
        #pragma unroll
        for (int kk = 0; kk < 2; ++kk) {
            bf16x8 af[4], bfr[4];
            #pragma unroll
            for (int m = 0; m < 4; ++m) {
                const int r = wr * 64 + m * 16 + laneR;
                af[m] = *(const bf16x8*)(smem + r * 128
                                         + (((kk * 4 + jb) ^ lx) * 16));
            }
            #pragma unroll
            for (int n = 0; n < 4; ++n) {
                const int r = wc * 64 + n * 16 + laneR;
                bfr[n] = *(const bf16x8*)(smem + 16384 + r * 128
                                          + (((kk * 4 + jb) ^ lx) * 16));
            }
            #pragma unroll
            for (int m = 0; m < 4; ++m)
                #pragma unroll
                for (int n = 0; n < 4; ++n)
                    acc[m][n] = __builtin_amdgcn_mfma_f32_16x16x32_bf16(
                        af[m], bfr[n], acc[m][n], 0, 0, 0);
        }
    };

    if constexpr (PRE) {
        const unsigned short* Abf = (const unsigned short*)Ap;
        const unsigned short* Bbf = (const unsigned short*)Bp;

        for (int kt = 0; kt < NKT; ++kt) {
            const int kofs = kt * BK;
            #pragma unroll
            for (int i = 0; i < 4; ++i) {
                gld_lds16(Abf + aoff0 + i * (32 * K_DIM) + kofs,
                          smem + i * 4096 + wave * 1024);
                gld_lds16(Bbf + boff0 + i * (32 * K_DIM) + kofs,
                          smem + 16384 + i * 4096 + wave * 1024);
            }
            __syncthreads();      // drains vmcnt(0): tile landed in LDS
            compute();
            __syncthreads();      // all reads done before next overwrite
        }
    } else {
        // fallback: fused fp32->bf16 reg-staging (no workspace needed)
        const float* Af = (const float*)Ap;
        const float* Bf = (const float*)Bp;
        f32x4 ra[4][2], rb[4][2];

        for (int kt = 0; kt < NKT; ++kt) {
            const int kofs = kt * BK;
            #pragma unroll
            for (int i = 0; i < 4; ++i) {
                const float* pa = Af + aoff0 + i * (32 * K_DIM) + kofs;
                ra[i][0] = *(const f32x4*)pa;
                ra[i][1] = *(const f32x4*)(pa + 4);
                const float* pb = Bf + boff0 + i * (32 * K_DIM) + kofs;
                rb[i][0] = *(const f32x4*)pb;
                rb[i][1] = *(const f32x4*)(pb + 4);
            }
            #pragma unroll
            for (int i = 0; i < 4; ++i) {
                bf16x8 oa, ob;
                #pragma unroll
                for (int q = 0; q < 4; ++q) {
                    oa[q]     = (short)f2bf(ra[i][0][q]);
                    oa[q + 4] = (short)f2bf(ra[i][1][q]);
                    ob[q]     = (short)f2bf(rb[i][0][q]);
                    ob[q + 4] = (short)f2bf(rb[i][1][q]);
                }
                *(bf16x8*)(smem + i * 4096 + t * 16) = oa;
                *(bf16x8*)(smem + 16384 + i * 4096 + t * 16) = ob;
            }
            __syncthreads();
            compute();
            __syncthreads();
        }
    }

    // epilogue: C/D layout col = lane&15, row = (lane>>4)*4 + reg
    const int cr = (lane >> 4) * 4;
    const int cc = lane & 15;
    float bv[4];
    #pragma unroll
    for (int n = 0; n < 4; ++n)
        bv[n] = bias[col0 + wc * 64 + n * 16 + cc];
    #pragma unroll
    for (int m = 0; m < 4; ++m) {
        const int gr = row0 + wr * 64 + m * 16 + cr;
        #pragma unroll
        for (int n = 0; n < 4; ++n) {
            const int gc = col0 + wc * 64 + n * 16 + cc;
            float* p = C + (size_t)gr * N_DIM + gc;
            p[0]                  = acc[m][n][0] + bv[n];
            p[(size_t)N_DIM]      = acc[m][n][1] + bv[n];
            p[(size_t)2 * N_DIM]  = acc[m][n][2] + bv[n];
            p[(size_t)3 * N_DIM]  = acc[m][n][3] + bv[n];
        }
    }
}

extern "C" void kernel_launch(void* const* d_in, const int* in_sizes, int n_in,
                              void* d_out, int out_size, void* d_ws, size_t ws_size,
                              hipStream_t stream) {
    const float* x    = (const float*)d_in[0];
    const float* w    = (const float*)d_in[1];
    const float* bias = (const float*)d_in[2];
    float* out        = (float*)d_out;

    const size_t needA = (size_t)M_DIM * K_DIM * sizeof(unsigned short);
    const size_t needB = (size_t)N_DIM * K_DIM * sizeof(unsigned short);

    if (ws_size >= needA + needB) {
        unsigned short* wsA = (unsigned short*)d_ws;
        unsigned short* wsB = wsA + (size_t)M_DIM * K_DIM;
        cast_kernel<<<4096, 256, 0, stream>>>(x, w, wsA, wsB);
        gemm_kernel<true><<<NWG, 256, 0, stream>>>(wsA, wsB, bias, out);
    } else {
        gemm_kernel<false><<<NWG, 256, 0, stream>>>(x, w, bias, out);
    }
}